// Round 2
// baseline (624.841 us; speedup 1.0000x reference)
//
#include <hip/hip_runtime.h>

#define N_NODES   100352
#define N_EDGES   1605632
#define IN_C      128
#define HID_C     64
#define OUT_C     32
#define NUM_GRAPHS 512
#define NPG       196
#define TOPK      30

// ws layout (bytes)
#define OFF_DEG     0u          // int[N]
#define OFF_ROWPTR  401408u     // int[N]
#define OFF_FILL    802816u     // int[N]
#define OFF_BSUM    1204224u    // int[98]
#define OFF_BOFF    1204736u    // int[98]
#define OFF_DIS     1205248u    // float[N]
#define OFF_CSR     1606656u    // int[E]
#define OFF_XW1     8029184u    // float[N*64]
#define OFF_H       33719296u   // float[N*64]
#define OFF_XW2     59409408u   // float[N*32]
#define OFF_OUT2    72254464u   // float[N*32]
// total: ~85 MB

__global__ void k_deg(const int* __restrict__ dst, int* __restrict__ deg) {
    int i = blockIdx.x * blockDim.x + threadIdx.x;
    if (i < N_EDGES) atomicAdd(&deg[dst[i]], 1);
}

__global__ __launch_bounds__(1024) void k_bsum(const int* __restrict__ deg, int* __restrict__ bsum) {
    __shared__ int s[1024];
    int t = threadIdx.x;
    s[t] = deg[blockIdx.x * 1024 + t];
    __syncthreads();
    for (int o = 512; o > 0; o >>= 1) {
        if (t < o) s[t] += s[t + o];
        __syncthreads();
    }
    if (t == 0) bsum[blockIdx.x] = s[0];
}

__global__ void k_bscan(const int* __restrict__ bsum, int* __restrict__ boff) {
    if (threadIdx.x == 0) {
        int run = 0;
        for (int b = 0; b < 98; ++b) { boff[b] = run; run += bsum[b]; }
    }
}

__global__ __launch_bounds__(1024) void k_scan(const int* __restrict__ deg, const int* __restrict__ boff,
                                               int* __restrict__ row_ptr, int* __restrict__ fill_pos,
                                               float* __restrict__ dis) {
    __shared__ int s[1024];
    int t = threadIdx.x;
    int i = blockIdx.x * 1024 + t;
    int v = deg[i];
    s[t] = v;
    __syncthreads();
    for (int o = 1; o < 1024; o <<= 1) {
        int a = (t >= o) ? s[t - o] : 0;
        __syncthreads();
        s[t] += a;
        __syncthreads();
    }
    int start = boff[blockIdx.x] + s[t] - v;   // exclusive prefix
    row_ptr[i] = start;
    fill_pos[i] = start;
    dis[i] = (float)(1.0 / sqrt((double)(v + 1)));   // +1 self-loop, correctly-rounded f32
}

__global__ void k_fill(const int* __restrict__ src, const int* __restrict__ dst,
                       int* __restrict__ fill_pos, int* __restrict__ csr_src) {
    int i = blockIdx.x * blockDim.x + threadIdx.x;
    if (i < N_EDGES) {
        int d = dst[i];
        int p = atomicAdd(&fill_pos[d], 1);
        csr_src[p] = src[i];
    }
}

// xw1 = x @ W1. One wave per 16 nodes; lane = output col; W1 column in VGPRs.
#define NPW1 16
__global__ __launch_bounds__(256) void k_mm1(const float* __restrict__ x, const float* __restrict__ W1,
                                             float* __restrict__ xw1) {
    int lane = threadIdx.x & 63;
    int wid = blockIdx.x * 4 + (threadIdx.x >> 6);   // global wave id
    float w[IN_C];
#pragma unroll
    for (int k = 0; k < IN_C; ++k)
        w[k] = W1[k * HID_C + lane];                 // coalesced across lanes
    int n0 = wid * NPW1;
    for (int nn = 0; nn < NPW1; ++nn) {
        int n = n0 + nn;
        const float4* xr = (const float4*)(x + (size_t)n * IN_C);  // wave-uniform → broadcast
        float acc = 0.f;
#pragma unroll
        for (int q = 0; q < IN_C / 4; ++q) {
            float4 xv = xr[q];
            acc = fmaf(xv.x, w[4 * q + 0], acc);
            acc = fmaf(xv.y, w[4 * q + 1], acc);
            acc = fmaf(xv.z, w[4 * q + 2], acc);
            acc = fmaf(xv.w, w[4 * q + 3], acc);
        }
        xw1[(size_t)n * HID_C + lane] = acc;
    }
}

// layer-1 aggregation: one 64-lane wave per node, lane = channel.
__global__ __launch_bounds__(256) void k_agg1(const float* __restrict__ xw1, const int* __restrict__ csr_src,
                                              const int* __restrict__ row_ptr, const int* __restrict__ deg,
                                              const float* __restrict__ dis, const float* __restrict__ b1,
                                              float* __restrict__ h) {
    int lane = threadIdx.x & 63;
    int v = blockIdx.x * 4 + (threadIdx.x >> 6);
    int start = row_ptr[v];
    int cnt = deg[v];
    float dv = dis[v];
    float acc = 0.f;
    for (int base = 0; base < cnt; base += 64) {
        int mcnt = min(64, cnt - base);
        int sj = 0; float dj = 0.f;
        if (lane < mcnt) { sj = csr_src[start + base + lane]; dj = dis[sj]; }
        for (int j = 0; j < mcnt; ++j) {
            int s = __shfl(sj, j);
            float ds = __shfl(dj, j);
            acc = fmaf(ds, xw1[(size_t)s * HID_C + lane], acc);
        }
    }
    float self = xw1[(size_t)v * HID_C + lane];
    float o = fmaf(dv, acc, fmaf(dv * dv, self, b1[lane]));
    h[(size_t)v * HID_C + lane] = fmaxf(o, 0.f);   // ReLU fused
}

// xw2 = h @ W2. One wave handles 2 nodes (lane>>5 selects), 16 node-pairs per wave.
#define NPW2 16
__global__ __launch_bounds__(256) void k_mm2(const float* __restrict__ h, const float* __restrict__ W2,
                                             float* __restrict__ xw2) {
    int lane = threadIdx.x & 63;
    int c = lane & 31;
    int half = lane >> 5;
    int wid = blockIdx.x * 4 + (threadIdx.x >> 6);
    float w[HID_C];
#pragma unroll
    for (int k = 0; k < HID_C; ++k)
        w[k] = W2[k * OUT_C + c];
    int p0 = wid * NPW2;
    for (int pp = 0; pp < NPW2; ++pp) {
        int n = (p0 + pp) * 2 + half;
        const float4* hr = (const float4*)(h + (size_t)n * HID_C);  // half-wave uniform
        float acc = 0.f;
#pragma unroll
        for (int q = 0; q < HID_C / 4; ++q) {
            float4 hv = hr[q];
            acc = fmaf(hv.x, w[4 * q + 0], acc);
            acc = fmaf(hv.y, w[4 * q + 1], acc);
            acc = fmaf(hv.z, w[4 * q + 2], acc);
            acc = fmaf(hv.w, w[4 * q + 3], acc);
        }
        xw2[(size_t)n * OUT_C + c] = acc;
    }
}

// layer-2 aggregation: 32-lane group per node.
__global__ __launch_bounds__(256) void k_agg2(const float* __restrict__ xw2, const int* __restrict__ csr_src,
                                              const int* __restrict__ row_ptr, const int* __restrict__ deg,
                                              const float* __restrict__ dis, const float* __restrict__ b2,
                                              float* __restrict__ out2) {
    int lane = threadIdx.x & 31;
    int v = blockIdx.x * 8 + (threadIdx.x >> 5);
    int start = row_ptr[v];
    int cnt = deg[v];
    float dv = dis[v];
    float acc = 0.f;
    for (int base = 0; base < cnt; base += 32) {
        int mcnt = min(32, cnt - base);
        int sj = 0; float dj = 0.f;
        if (lane < mcnt) { sj = csr_src[start + base + lane]; dj = dis[sj]; }
        for (int j = 0; j < mcnt; ++j) {
            int s = __shfl(sj, j, 32);
            float ds = __shfl(dj, j, 32);
            acc = fmaf(ds, xw2[(size_t)s * OUT_C + lane], acc);
        }
    }
    float self = xw2[(size_t)v * OUT_C + lane];
    out2[(size_t)v * OUT_C + lane] = fmaf(dv, acc, fmaf(dv * dv, self, b2[lane]));
}

// per-graph top-30 by channel 31 (desc, stable), emit [512, 30*32] f32.
__global__ __launch_bounds__(256) void k_sort(const float* __restrict__ out2, float* __restrict__ out) {
    __shared__ float keys[NPG];
    __shared__ int order[TOPK];
    int g = blockIdx.x;
    int tid = threadIdx.x;
    int base = g * NPG;
    if (tid < NPG) keys[tid] = out2[(size_t)(base + tid) * OUT_C + (OUT_C - 1)];
    __syncthreads();
    if (tid < NPG) {
        float my = keys[tid];
        int r = 0;
        for (int j = 0; j < NPG; ++j) {
            float kj = keys[j];
            r += (kj > my) || (kj == my && j < tid);
        }
        if (r < TOPK) order[r] = tid;
    }
    __syncthreads();
    for (int idx = tid; idx < TOPK * OUT_C; idx += 256) {
        int r = idx >> 5;
        int c = idx & 31;
        int n = order[r];
        out[g * (TOPK * OUT_C) + idx] = out2[(size_t)(base + n) * OUT_C + c];
    }
}

extern "C" void kernel_launch(void* const* d_in, const int* in_sizes, int n_in,
                              void* d_out, int out_size, void* d_ws, size_t ws_size,
                              hipStream_t stream) {
    const float* x  = (const float*)d_in[0];
    const int*   ei = (const int*)d_in[1];
    const int*   srcp = ei;             // edge_index[0]
    const int*   dstp = ei + N_EDGES;   // edge_index[1]
    // d_in[2] (batch) unused: graphs are contiguous 196-node blocks.
    const float* W1 = (const float*)d_in[3];
    const float* b1 = (const float*)d_in[4];
    const float* W2 = (const float*)d_in[5];
    const float* b2 = (const float*)d_in[6];
    float* out = (float*)d_out;

    char* w = (char*)d_ws;
    int*    deg      = (int*)(w + OFF_DEG);
    int*    row_ptr  = (int*)(w + OFF_ROWPTR);
    int*    fill_pos = (int*)(w + OFF_FILL);
    int*    bsum     = (int*)(w + OFF_BSUM);
    int*    boff     = (int*)(w + OFF_BOFF);
    float*  dis      = (float*)(w + OFF_DIS);
    int*    csr_src  = (int*)(w + OFF_CSR);
    float*  xw1      = (float*)(w + OFF_XW1);
    float*  h        = (float*)(w + OFF_H);
    float*  xw2      = (float*)(w + OFF_XW2);
    float*  out2     = (float*)(w + OFF_OUT2);

    hipMemsetAsync(deg, 0, N_NODES * sizeof(int), stream);
    k_deg  <<<(N_EDGES + 255) / 256, 256, 0, stream>>>(dstp, deg);
    k_bsum <<<98, 1024, 0, stream>>>(deg, bsum);
    k_bscan<<<1, 64, 0, stream>>>(bsum, boff);
    k_scan <<<98, 1024, 0, stream>>>(deg, boff, row_ptr, fill_pos, dis);
    k_fill <<<(N_EDGES + 255) / 256, 256, 0, stream>>>(srcp, dstp, fill_pos, csr_src);
    k_mm1  <<<N_NODES / (NPW1 * 4), 256, 0, stream>>>(x, W1, xw1);
    k_agg1 <<<N_NODES / 4, 256, 0, stream>>>(xw1, csr_src, row_ptr, deg, dis, b1, h);
    k_mm2  <<<N_NODES / (NPW2 * 2 * 4), 256, 0, stream>>>(h, W2, xw2);
    k_agg2 <<<N_NODES / 8, 256, 0, stream>>>(xw2, csr_src, row_ptr, deg, dis, b2, out2);
    k_sort <<<NUM_GRAPHS, 256, 0, stream>>>(out2, out);
}